// Round 3
// baseline (271.828 us; speedup 1.0000x reference)
//
#include <hip/hip_runtime.h>
#include <math.h>

// ---------------- helpers ----------------
typedef short short8 __attribute__((ext_vector_type(8)));
typedef float floatx4 __attribute__((ext_vector_type(4)));

#define CHUNK_SHIFT 13  // 8192-node chunks: 2MB gather window within each row's neighbor list
#define NCHUNK 8

__device__ __forceinline__ float4 ld4(const float* p) { return *reinterpret_cast<const float4*>(p); }
__device__ __forceinline__ void st4(float* p, float4 v) { *reinterpret_cast<float4*>(p) = v; }

__device__ __forceinline__ float bf2f(unsigned int u) { return __uint_as_float(u << 16); }
__device__ __forceinline__ unsigned int f2bf1(float f) {
    unsigned int x = __float_as_uint(f);
    return (x + 0x7fffu + ((x >> 16) & 1u)) >> 16;  // RNE
}
__device__ __forceinline__ unsigned int f2bf2(float lo, float hi) {
    return f2bf1(lo) | (f2bf1(hi) << 16);
}
__device__ __forceinline__ void unpack8(uint4 v, float* f) {
    f[0] = bf2f(v.x & 0xffffu); f[1] = bf2f(v.x >> 16);
    f[2] = bf2f(v.y & 0xffffu); f[3] = bf2f(v.y >> 16);
    f[4] = bf2f(v.z & 0xffffu); f[5] = bf2f(v.z >> 16);
    f[6] = bf2f(v.w & 0xffffu); f[7] = bf2f(v.w >> 16);
}

__device__ __forceinline__ int sum8(const int* __restrict__ p) {
    uint4 a = *reinterpret_cast<const uint4*>(p);
    uint4 b = *reinterpret_cast<const uint4*>(p + 4);
    return (int)(a.x + a.y + a.z + a.w + b.x + b.y + b.z + b.w);
}

// ---------------- launch A: edge count/rank per (dst,chunk) + all-W transpose ----------------
__global__ __launch_bounds__(256) void k_count_prep(const int* __restrict__ src, const int* __restrict__ dst,
                                                    int* __restrict__ deg2, int* __restrict__ rank, int E, int nbE,
                                                    const float* __restrict__ W1, const float* __restrict__ W2,
                                                    const float* __restrict__ W3, unsigned short* __restrict__ Wt1,
                                                    unsigned short* __restrict__ Wt2, unsigned short* __restrict__ Wt3) {
    if ((int)blockIdx.x < nbE) {
        int e = blockIdx.x * 256 + threadIdx.x;
        if (e < E) {
            int c = src[e] >> CHUNK_SHIFT;
            rank[e] = atomicAdd(&deg2[dst[e] * NCHUNK + c], 1);
        }
    } else {
        int t = (blockIdx.x - nbE) * 256 + threadIdx.x;
        if (t < 16384) {
            int k = t & 127, n = t >> 7;
            Wt1[n * 128 + k] = (unsigned short)f2bf1(W1[(size_t)k * 128 + n]);
        } else if (t < 32768) {
            int u = t - 16384;
            int k = u & 127, n = u >> 7;
            Wt2[n * 128 + k] = (unsigned short)f2bf1(W2[(size_t)k * 128 + n]);
        } else if (t < 40960) {
            int u = t - 32768;
            int k = u & 127, n = u >> 7;
            Wt3[n * 128 + k] = (unsigned short)f2bf1(W3[(size_t)k * 64 + n]);
        }
    }
}

// ---------------- launch B: dinv (blocks [0,nbN)) + deg block-reduce ----------------
__global__ __launch_bounds__(256) void k_dinv_reduce(const int* __restrict__ deg2, float* __restrict__ dinv,
                                                     int* __restrict__ bsum, int n, int nbN) {
    __shared__ int s[256];
    int t = threadIdx.x;
    if ((int)blockIdx.x < nbN) {
        int i = blockIdx.x * 256 + t;
        if (i < n) {
            int d = sum8(deg2 + (size_t)i * NCHUNK);
            dinv[i] = 1.0f / sqrtf((float)d + 1.0f);
        }
        return;
    }
    int b = (int)blockIdx.x - nbN;
    int i = b * 256 + t;
    s[t] = (i < n) ? sum8(deg2 + (size_t)i * NCHUNK) : 0;
    __syncthreads();
    for (int off = 128; off > 0; off >>= 1) {
        if (t < off) s[t] += s[t + off];
        __syncthreads();
    }
    if (t == 0) bsum[b] = s[0];
}

// ---------------- launch C: scan_small (block 0) + layer-1 MFMA GEMM (dinv pre-scale) ----------------
__global__ __launch_bounds__(256) void k_scansmall_gemm1(const int* __restrict__ bsum, int* __restrict__ boff, int nb,
                                                         const float* __restrict__ X, const unsigned short* __restrict__ Wt,
                                                         const float* __restrict__ dinv,
                                                         unsigned short* __restrict__ O, int nrows) {
    constexpr int LDR = 136;
    __shared__ __align__(16) unsigned char smem[(64 * LDR + 128 * LDR) * 2];  // 52224 B

    const int tid = threadIdx.x;
    if (blockIdx.x == 0) {
        int* s = (int*)smem;
        int v = (tid < nb) ? bsum[tid] : 0;
        s[tid] = v;
        __syncthreads();
        for (int off = 1; off < 256; off <<= 1) {
            int x = (tid >= off) ? s[tid - off] : 0;
            __syncthreads();
            s[tid] += x;
            __syncthreads();
        }
        if (tid < nb) boff[tid] = s[tid] - v;  // exclusive
        return;
    }

    unsigned short* sX = (unsigned short*)smem;
    unsigned short* sB = sX + 64 * LDR;
    const int row0 = ((int)blockIdx.x - 1) * 64;

#pragma unroll
    for (int i = 0; i < 4; ++i) {
        int idx = tid + i * 256;
        int r = idx >> 4, c8 = idx & 15;
        int grow = row0 + r;
        uint4 v = make_uint4(0, 0, 0, 0);
        if (grow < nrows) {
            float4 a = ld4(X + (size_t)grow * 128 + c8 * 8);
            float4 b = ld4(X + (size_t)grow * 128 + c8 * 8 + 4);
            v = make_uint4(f2bf2(a.x, a.y), f2bf2(a.z, a.w), f2bf2(b.x, b.y), f2bf2(b.z, b.w));
        }
        *reinterpret_cast<uint4*>(&sX[r * LDR + c8 * 8]) = v;
    }
#pragma unroll
    for (int i = 0; i < 8; ++i) {
        int idx = tid + i * 256;
        int nn = idx >> 4, c8 = idx & 15;
        *reinterpret_cast<uint4*>(&sB[nn * LDR + c8 * 8]) =
            *reinterpret_cast<const uint4*>(Wt + (size_t)nn * 128 + c8 * 8);
    }
    __syncthreads();

    const int lane = tid & 63;
    const int wave = tid >> 6;
    const int l15  = lane & 15;
    const int quad = lane >> 4;

    floatx4 acc[8];
#pragma unroll
    for (int j = 0; j < 8; ++j) acc[j] = (floatx4){0.f, 0.f, 0.f, 0.f};

    const unsigned short* xbase = &sX[(wave * 16 + l15) * LDR + quad * 8];
#pragma unroll
    for (int kk = 0; kk < 4; ++kk) {
        short8 xb = *reinterpret_cast<const short8*>(xbase + kk * 32);
#pragma unroll
        for (int j = 0; j < 8; ++j) {
            short8 wa = *reinterpret_cast<const short8*>(&sB[(j * 16 + l15) * LDR + quad * 8 + kk * 32]);
            acc[j] = __builtin_amdgcn_mfma_f32_16x16x32_bf16(wa, xb, acc[j], 0, 0, 0);
        }
    }

    int xrow = row0 + wave * 16 + l15;
    if (xrow < nrows) {
        float di = dinv[xrow];
#pragma unroll
        for (int j = 0; j < 8; ++j) {
            uint2 o = make_uint2(f2bf2(acc[j][0] * di, acc[j][1] * di), f2bf2(acc[j][2] * di, acc[j][3] * di));
            *reinterpret_cast<uint2*>(O + (size_t)xrow * 128 + j * 16 + quad * 4) = o;
        }
    }
}

// ---------------- launch D: final scan -> row_off + per-(node,chunk) starts2 ----------------
__global__ __launch_bounds__(256) void k_scan_final(const int* __restrict__ deg2, const int* __restrict__ boff,
                                                    int* __restrict__ row_off, int* __restrict__ starts2,
                                                    int n) {
    __shared__ int s[256];
    int t = threadIdx.x;
    int i = blockIdx.x * 256 + t;
    uint4 d0 = make_uint4(0, 0, 0, 0), d1 = make_uint4(0, 0, 0, 0);
    int tot = 0;
    if (i < n) {
        d0 = *reinterpret_cast<const uint4*>(deg2 + (size_t)i * NCHUNK);
        d1 = *reinterpret_cast<const uint4*>(deg2 + (size_t)i * NCHUNK + 4);
        tot = (int)(d0.x + d0.y + d0.z + d0.w + d1.x + d1.y + d1.z + d1.w);
    }
    s[t] = tot;
    __syncthreads();
    for (int off = 1; off < 256; off <<= 1) {
        int x = (t >= off) ? s[t - off] : 0;
        __syncthreads();
        s[t] += x;
        __syncthreads();
    }
    int incl = s[t] + boff[blockIdx.x];
    if (i < n) {
        int r = incl - tot;
        row_off[i] = r;
        uint4 o0, o1;
        o0.x = r; r += d0.x;
        o0.y = r; r += d0.y;
        o0.z = r; r += d0.z;
        o0.w = r; r += d0.w;
        o1.x = r; r += d1.x;
        o1.y = r; r += d1.y;
        o1.z = r; r += d1.z;
        o1.w = r;
        *reinterpret_cast<uint4*>(starts2 + (size_t)i * NCHUNK) = o0;
        *reinterpret_cast<uint4*>(starts2 + (size_t)i * NCHUNK + 4) = o1;
        if (i == n - 1) row_off[n] = incl;
    }
}

// ---------------- launch E: CSR fill (chunk-ordered within each row) ----------------
__global__ __launch_bounds__(256) void k_fill(const int* __restrict__ src, const int* __restrict__ dst,
                                              const int* __restrict__ rank, const int* __restrict__ starts2,
                                              int* __restrict__ csrc, int E) {
    int e = blockIdx.x * 256 + threadIdx.x;
    if (e < E) {
        int s = src[e];
        int c = s >> CHUNK_SHIFT;
        csrc[starts2[dst[e] * NCHUNK + c] + rank[e]] = s;
    }
}

// ---------------- FUSED: aggregation(+bias+relu) of 64 rows -> LDS -> MFMA GEMM ----------------
// H: previous layer's pre-scaled H' [n][128] bf16. Output O[n][NC] = (relu(dinv*(sum+self)+bias) @ W) * dinv.
// Phase 1: each thread owns 4 node-slots (concurrent, 16 independent gathers in flight) x 8 feats.
// Phase 2: standard 64-row MFMA GEMM out of LDS.
template <int NC>
__global__ __launch_bounds__(256) void k_agg_gemm(const unsigned short* __restrict__ H,
                                                  const int* __restrict__ roff,
                                                  const int* __restrict__ csrc,
                                                  const float* __restrict__ dinv,
                                                  const float* __restrict__ bias,
                                                  const unsigned short* __restrict__ Wt,
                                                  unsigned short* __restrict__ O, int n) {
    constexpr int LDR = 136;
    __shared__ unsigned short sX[64 * LDR];
    __shared__ unsigned short sB[NC * LDR];

    const int tid  = threadIdx.x;
    const int row0 = blockIdx.x * 64;

    // stage W tile early (independent of agg phase; covered by the single barrier below)
#pragma unroll
    for (int i = 0; i < NC / 16; ++i) {
        int idx = tid + i * 256;
        int nn = idx >> 4, c8 = idx & 15;
        *reinterpret_cast<uint4*>(&sB[nn * LDR + c8 * 8]) =
            *reinterpret_cast<const uint4*>(Wt + (size_t)nn * 128 + c8 * 8);
    }

    // ---- phase 1: aggregate ----
    const int nl = tid >> 4;        // 0..15
    const int f8 = (tid & 15) * 8;  // feature offset (x8 floats)

    float a[4][8];
    int e[4], e1[4];
#pragma unroll
    for (int s = 0; s < 4; ++s) {
        int node = row0 + s * 16 + nl;
        if (node < n) {
            uint4 hv = *reinterpret_cast<const uint4*>(H + (size_t)node * 128 + f8);
            unpack8(hv, a[s]);  // self term
            e[s]  = roff[node];
            e1[s] = roff[node + 1];
        } else {
#pragma unroll
            for (int i = 0; i < 8; ++i) a[s][i] = 0.0f;
            e[s] = 0; e1[s] = 0;
        }
    }

    int mb = 0;
#pragma unroll
    for (int s = 0; s < 4; ++s) mb = max(mb, (e1[s] - e[s] + 3) >> 2);

    for (int b = 0; b < mb; ++b) {
#pragma unroll
        for (int s = 0; s < 4; ++s) {
            if (e[s] >= e1[s]) continue;
            int idx[4]; float mk[4];
#pragma unroll
            for (int u = 0; u < 4; ++u) {
                bool ok = (e[s] + u) < e1[s];
                idx[u] = ok ? csrc[e[s] + u] : 0;
                mk[u]  = ok ? 1.0f : 0.0f;
            }
            uint4 v[4];
#pragma unroll
            for (int u = 0; u < 4; ++u) v[u] = *reinterpret_cast<const uint4*>(H + (size_t)idx[u] * 128 + f8);
#pragma unroll
            for (int u = 0; u < 4; ++u) {
                float g[8];
                unpack8(v[u], g);
#pragma unroll
                for (int i = 0; i < 8; ++i) a[s][i] = fmaf(mk[u], g[i], a[s][i]);
            }
            e[s] += 4;
        }
    }

    // epilogue: dinv scale + bias + relu, store bf16 row slice into sX
    float4 b0 = ld4(bias + f8);
    float4 b1 = ld4(bias + f8 + 4);
    float bb[8] = {b0.x, b0.y, b0.z, b0.w, b1.x, b1.y, b1.z, b1.w};
#pragma unroll
    for (int s = 0; s < 4; ++s) {
        int node = row0 + s * 16 + nl;
        float di = (node < n) ? dinv[node] : 0.0f;
#pragma unroll
        for (int i = 0; i < 8; ++i) a[s][i] = fmaxf(a[s][i] * di + bb[i], 0.0f);
        uint4 ov = make_uint4(f2bf2(a[s][0], a[s][1]), f2bf2(a[s][2], a[s][3]),
                              f2bf2(a[s][4], a[s][5]), f2bf2(a[s][6], a[s][7]));
        *reinterpret_cast<uint4*>(&sX[(s * 16 + nl) * LDR + f8]) = ov;
    }
    __syncthreads();

    // ---- phase 2: GEMM ----
    const int lane = tid & 63;
    const int wave = tid >> 6;
    const int l15  = lane & 15;
    const int quad = lane >> 4;

    floatx4 acc[NC / 16];
#pragma unroll
    for (int j = 0; j < NC / 16; ++j) acc[j] = (floatx4){0.f, 0.f, 0.f, 0.f};

    const unsigned short* xbase = &sX[(wave * 16 + l15) * LDR + quad * 8];
#pragma unroll
    for (int kk = 0; kk < 4; ++kk) {
        short8 xb = *reinterpret_cast<const short8*>(xbase + kk * 32);
#pragma unroll
        for (int j = 0; j < NC / 16; ++j) {
            short8 wa = *reinterpret_cast<const short8*>(&sB[(j * 16 + l15) * LDR + quad * 8 + kk * 32]);
            acc[j] = __builtin_amdgcn_mfma_f32_16x16x32_bf16(wa, xb, acc[j], 0, 0, 0);
        }
    }

    int xrow = row0 + wave * 16 + l15;
    if (xrow < n) {
        float di = dinv[xrow];
#pragma unroll
        for (int j = 0; j < NC / 16; ++j) {
            uint2 o = make_uint2(f2bf2(acc[j][0] * di, acc[j][1] * di), f2bf2(acc[j][2] * di, acc[j][3] * di));
            *reinterpret_cast<uint2*>(O + (size_t)xrow * NC + j * 16 + quad * 4) = o;
        }
    }
}

// ---------------- aggregation (64 feats, pre-scaled bf16 H') + bias + log_softmax ----------------
__global__ __launch_bounds__(256) void k_agg_softmax(const unsigned short* __restrict__ H, const int* __restrict__ roff,
                                                     const int* __restrict__ csrc, const float* __restrict__ dinv,
                                                     const float* __restrict__ bias, float* __restrict__ O, int n) {
    int t    = blockIdx.x * 256 + threadIdx.x;
    int node = t >> 3;
    int f8   = (t & 7) * 8;
    if (node >= n) return;

    float a[8];
    {
        uint4 hv = *reinterpret_cast<const uint4*>(H + (size_t)node * 64 + f8);
        unpack8(hv, a);  // self term
    }

    int e  = roff[node];
    int e1 = roff[node + 1];
    for (; e + 7 < e1; e += 8) {
        int s[8];
        uint4 v[8];
#pragma unroll
        for (int u = 0; u < 8; ++u) s[u] = csrc[e + u];
#pragma unroll
        for (int u = 0; u < 8; ++u) v[u] = *reinterpret_cast<const uint4*>(H + (size_t)s[u] * 64 + f8);
#pragma unroll
        for (int u = 0; u < 8; ++u) {
            float gg[8];
            unpack8(v[u], gg);
#pragma unroll
            for (int i = 0; i < 8; ++i) a[i] += gg[i];
        }
    }
    if (e + 3 < e1) {
        int s[4];
        uint4 v[4];
#pragma unroll
        for (int u = 0; u < 4; ++u) s[u] = csrc[e + u];
#pragma unroll
        for (int u = 0; u < 4; ++u) v[u] = *reinterpret_cast<const uint4*>(H + (size_t)s[u] * 64 + f8);
#pragma unroll
        for (int u = 0; u < 4; ++u) {
            float gg[8];
            unpack8(v[u], gg);
#pragma unroll
            for (int i = 0; i < 8; ++i) a[i] += gg[i];
        }
        e += 4;
    }
    for (; e < e1; ++e) {
        uint4 v0 = *reinterpret_cast<const uint4*>(H + (size_t)csrc[e] * 64 + f8);
        float g0[8];
        unpack8(v0, g0);
#pragma unroll
        for (int i = 0; i < 8; ++i) a[i] += g0[i];
    }

    float di = dinv[node];
    float4 b0 = ld4(bias + f8);
    float4 b1 = ld4(bias + f8 + 4);
    float bb[8] = {b0.x, b0.y, b0.z, b0.w, b1.x, b1.y, b1.z, b1.w};
    float v[8];
#pragma unroll
    for (int i = 0; i < 8; ++i) v[i] = a[i] * di + bb[i];

    float m = v[0];
#pragma unroll
    for (int i = 1; i < 8; ++i) m = fmaxf(m, v[i]);
    m = fmaxf(m, __shfl_xor(m, 1));
    m = fmaxf(m, __shfl_xor(m, 2));
    m = fmaxf(m, __shfl_xor(m, 4));

    float ssum = 0.0f;
#pragma unroll
    for (int i = 0; i < 8; ++i) ssum += expf(v[i] - m);
    ssum += __shfl_xor(ssum, 1);
    ssum += __shfl_xor(ssum, 2);
    ssum += __shfl_xor(ssum, 4);
    float ls = logf(ssum);

    float* op = O + (size_t)node * 64 + f8;
    st4(op, make_float4(v[0] - m - ls, v[1] - m - ls, v[2] - m - ls, v[3] - m - ls));
    st4(op + 4, make_float4(v[4] - m - ls, v[5] - m - ls, v[6] - m - ls, v[7] - m - ls));
}

// ---------------- launch ----------------
extern "C" void kernel_launch(void* const* d_in, const int* in_sizes, int n_in,
                              void* d_out, int out_size, void* d_ws, size_t ws_size,
                              hipStream_t stream) {
    const float* x  = (const float*)d_in[0];
    const int*   ei = (const int*)d_in[1];
    const float* W1 = (const float*)d_in[2];
    const float* b1 = (const float*)d_in[3];
    const float* W2 = (const float*)d_in[4];
    const float* b2 = (const float*)d_in[5];
    const float* W3 = (const float*)d_in[6];
    const float* b3 = (const float*)d_in[7];
    float* out = (float*)d_out;

    const int N = in_sizes[0] / 128;
    const int E = in_sizes[1] / 2;
    const int* src = ei;
    const int* dst = ei + E;

    char* ws = (char*)d_ws;
    size_t off = 0;
    auto alloc = [&](size_t bytes) -> char* {
        char* p = ws + off;
        off = (off + bytes + 255) & ~(size_t)255;
        return p;
    };
    int nb  = (N + 255) / 256;
    int nbE = (E + 255) / 256;
    int blocks64 = (N + 63) / 64;

    int*   deg2    = (int*)alloc((size_t)N * NCHUNK * 4);
    int*   row_off = (int*)alloc(((size_t)N + 1) * 4);
    int*   starts2 = (int*)alloc((size_t)N * NCHUNK * 4);
    float* dinv    = (float*)alloc((size_t)N * 4);
    int*   bsum    = (int*)alloc((size_t)nb * 4);
    int*   boff    = (int*)alloc((size_t)nb * 4);
    int*   rank    = (int*)alloc((size_t)E * 4);
    int*   csrc    = (int*)alloc((size_t)E * 4);
    unsigned short* Wt1  = (unsigned short*)alloc(128 * 128 * 2);
    unsigned short* Wt2  = (unsigned short*)alloc(128 * 128 * 2);
    unsigned short* Wt3  = (unsigned short*)alloc(64 * 128 * 2);
    unsigned short* bufA = (unsigned short*)alloc((size_t)N * 128 * 2);
    unsigned short* bufB = (unsigned short*)alloc((size_t)N * 128 * 2);
    unsigned short* bufC = (unsigned short*)alloc((size_t)N * 64 * 2);
    (void)ws_size; (void)n_in; (void)out_size;

    hipMemsetAsync(deg2, 0, (size_t)N * NCHUNK * 4, stream);
    // A: edge count/rank per (dst,chunk) + W transposes
    k_count_prep<<<nbE + 160, 256, 0, stream>>>(src, dst, deg2, rank, E, nbE, W1, W2, W3, Wt1, Wt2, Wt3);
    // B: dinv + deg block-reduce
    k_dinv_reduce<<<nb + nb, 256, 0, stream>>>(deg2, dinv, bsum, N, nb);
    // C: scan_small (block 0) + layer-1 GEMM pre-scaled by dinv
    k_scansmall_gemm1<<<1 + blocks64, 256, 0, stream>>>(bsum, boff, nb, x, Wt1, dinv, bufA, N);
    // D: final scan -> row_off + starts2
    k_scan_final<<<nb, 256, 0, stream>>>(deg2, boff, row_off, starts2, N);
    // E: CSR fill (chunk-ordered)
    k_fill<<<nbE, 256, 0, stream>>>(src, dst, rank, starts2, csrc, E);

    // fused layer-1 agg (+b1+relu) -> layer-2 GEMM (pre-scaled out)
    k_agg_gemm<128><<<blocks64, 256, 0, stream>>>(bufA, row_off, csrc, dinv, b1, Wt2, bufB, N);
    // fused layer-2 agg (+b2+relu) -> layer-3 GEMM (pre-scaled out, 64 cols)
    k_agg_gemm<64><<<blocks64, 256, 0, stream>>>(bufB, row_off, csrc, dinv, b2, Wt3, bufC, N);
    // layer-3 aggregation + bias + log_softmax
    k_agg_softmax<<<((size_t)N * 8 + 255) / 256, 256, 0, stream>>>(bufC, row_off, csrc, dinv, b3, out, N);
}

// Round 4
// 250.046 us; speedup vs baseline: 1.0871x; 1.0871x over previous
//
#include <hip/hip_runtime.h>
#include <math.h>

// ---------------- helpers ----------------
typedef short short8 __attribute__((ext_vector_type(8)));
typedef float floatx4 __attribute__((ext_vector_type(4)));

#define CHUNK_SHIFT 13  // 8192-node chunks: 2MB gather window within each row's neighbor list
#define NCHUNK 8

__device__ __forceinline__ float4 ld4(const float* p) { return *reinterpret_cast<const float4*>(p); }
__device__ __forceinline__ void st4(float* p, float4 v) { *reinterpret_cast<float4*>(p) = v; }

__device__ __forceinline__ float bf2f(unsigned int u) { return __uint_as_float(u << 16); }
__device__ __forceinline__ unsigned int f2bf1(float f) {
    unsigned int x = __float_as_uint(f);
    return (x + 0x7fffu + ((x >> 16) & 1u)) >> 16;  // RNE
}
__device__ __forceinline__ unsigned int f2bf2(float lo, float hi) {
    return f2bf1(lo) | (f2bf1(hi) << 16);
}
__device__ __forceinline__ void unpack8(uint4 v, float* f) {
    f[0] = bf2f(v.x & 0xffffu); f[1] = bf2f(v.x >> 16);
    f[2] = bf2f(v.y & 0xffffu); f[3] = bf2f(v.y >> 16);
    f[4] = bf2f(v.z & 0xffffu); f[5] = bf2f(v.z >> 16);
    f[6] = bf2f(v.w & 0xffffu); f[7] = bf2f(v.w >> 16);
}

__device__ __forceinline__ int sum8(const int* __restrict__ p) {
    uint4 a = *reinterpret_cast<const uint4*>(p);
    uint4 b = *reinterpret_cast<const uint4*>(p + 4);
    return (int)(a.x + a.y + a.z + a.w + b.x + b.y + b.z + b.w);
}

// ---------------- launch A: edge count/rank per (dst,chunk) + all-W transpose ----------------
__global__ __launch_bounds__(256) void k_count_prep(const int* __restrict__ src, const int* __restrict__ dst,
                                                    int* __restrict__ deg2, int* __restrict__ rank, int E, int nbE,
                                                    const float* __restrict__ W1, const float* __restrict__ W2,
                                                    const float* __restrict__ W3, unsigned short* __restrict__ Wt1,
                                                    unsigned short* __restrict__ Wt2, unsigned short* __restrict__ Wt3) {
    if ((int)blockIdx.x < nbE) {
        int e = blockIdx.x * 256 + threadIdx.x;
        if (e < E) {
            int c = src[e] >> CHUNK_SHIFT;
            rank[e] = atomicAdd(&deg2[dst[e] * NCHUNK + c], 1);
        }
    } else {
        int t = (blockIdx.x - nbE) * 256 + threadIdx.x;
        if (t < 16384) {
            int k = t & 127, n = t >> 7;
            Wt1[n * 128 + k] = (unsigned short)f2bf1(W1[(size_t)k * 128 + n]);
        } else if (t < 32768) {
            int u = t - 16384;
            int k = u & 127, n = u >> 7;
            Wt2[n * 128 + k] = (unsigned short)f2bf1(W2[(size_t)k * 128 + n]);
        } else if (t < 40960) {
            int u = t - 32768;
            int k = u & 127, n = u >> 7;
            Wt3[n * 128 + k] = (unsigned short)f2bf1(W3[(size_t)k * 64 + n]);
        }
    }
}

// ---------------- launch B: dinv (blocks [0,nbN)) + deg block-reduce ----------------
__global__ __launch_bounds__(256) void k_dinv_reduce(const int* __restrict__ deg2, float* __restrict__ dinv,
                                                     int* __restrict__ bsum, int n, int nbN) {
    __shared__ int s[256];
    int t = threadIdx.x;
    if ((int)blockIdx.x < nbN) {
        int i = blockIdx.x * 256 + t;
        if (i < n) {
            int d = sum8(deg2 + (size_t)i * NCHUNK);
            dinv[i] = 1.0f / sqrtf((float)d + 1.0f);
        }
        return;
    }
    int b = (int)blockIdx.x - nbN;
    int i = b * 256 + t;
    s[t] = (i < n) ? sum8(deg2 + (size_t)i * NCHUNK) : 0;
    __syncthreads();
    for (int off = 128; off > 0; off >>= 1) {
        if (t < off) s[t] += s[t + off];
        __syncthreads();
    }
    if (t == 0) bsum[b] = s[0];
}

// ---------------- launch C: scan_small (block 0) + layer-1 MFMA GEMM (dinv pre-scale) ----------------
__global__ __launch_bounds__(256) void k_scansmall_gemm1(const int* __restrict__ bsum, int* __restrict__ boff, int nb,
                                                         const float* __restrict__ X, const unsigned short* __restrict__ Wt,
                                                         const float* __restrict__ dinv,
                                                         unsigned short* __restrict__ O, int nrows) {
    constexpr int LDR = 136;
    __shared__ __align__(16) unsigned char smem[(64 * LDR + 128 * LDR) * 2];  // 52224 B

    const int tid = threadIdx.x;
    if (blockIdx.x == 0) {
        int* s = (int*)smem;
        int v = (tid < nb) ? bsum[tid] : 0;
        s[tid] = v;
        __syncthreads();
        for (int off = 1; off < 256; off <<= 1) {
            int x = (tid >= off) ? s[tid - off] : 0;
            __syncthreads();
            s[tid] += x;
            __syncthreads();
        }
        if (tid < nb) boff[tid] = s[tid] - v;  // exclusive
        return;
    }

    unsigned short* sX = (unsigned short*)smem;
    unsigned short* sB = sX + 64 * LDR;
    const int row0 = ((int)blockIdx.x - 1) * 64;

#pragma unroll
    for (int i = 0; i < 4; ++i) {
        int idx = tid + i * 256;
        int r = idx >> 4, c8 = idx & 15;
        int grow = row0 + r;
        uint4 v = make_uint4(0, 0, 0, 0);
        if (grow < nrows) {
            float4 a = ld4(X + (size_t)grow * 128 + c8 * 8);
            float4 b = ld4(X + (size_t)grow * 128 + c8 * 8 + 4);
            v = make_uint4(f2bf2(a.x, a.y), f2bf2(a.z, a.w), f2bf2(b.x, b.y), f2bf2(b.z, b.w));
        }
        *reinterpret_cast<uint4*>(&sX[r * LDR + c8 * 8]) = v;
    }
#pragma unroll
    for (int i = 0; i < 8; ++i) {
        int idx = tid + i * 256;
        int nn = idx >> 4, c8 = idx & 15;
        *reinterpret_cast<uint4*>(&sB[nn * LDR + c8 * 8]) =
            *reinterpret_cast<const uint4*>(Wt + (size_t)nn * 128 + c8 * 8);
    }
    __syncthreads();

    const int lane = tid & 63;
    const int wave = tid >> 6;
    const int l15  = lane & 15;
    const int quad = lane >> 4;

    floatx4 acc[8];
#pragma unroll
    for (int j = 0; j < 8; ++j) acc[j] = (floatx4){0.f, 0.f, 0.f, 0.f};

    const unsigned short* xbase = &sX[(wave * 16 + l15) * LDR + quad * 8];
#pragma unroll
    for (int kk = 0; kk < 4; ++kk) {
        short8 xb = *reinterpret_cast<const short8*>(xbase + kk * 32);
#pragma unroll
        for (int j = 0; j < 8; ++j) {
            short8 wa = *reinterpret_cast<const short8*>(&sB[(j * 16 + l15) * LDR + quad * 8 + kk * 32]);
            acc[j] = __builtin_amdgcn_mfma_f32_16x16x32_bf16(wa, xb, acc[j], 0, 0, 0);
        }
    }

    int xrow = row0 + wave * 16 + l15;
    if (xrow < nrows) {
        float di = dinv[xrow];
#pragma unroll
        for (int j = 0; j < 8; ++j) {
            uint2 o = make_uint2(f2bf2(acc[j][0] * di, acc[j][1] * di), f2bf2(acc[j][2] * di, acc[j][3] * di));
            *reinterpret_cast<uint2*>(O + (size_t)xrow * 128 + j * 16 + quad * 4) = o;
        }
    }
}

// ---------------- launch D: final scan -> row_off + per-(node,chunk) starts2 ----------------
__global__ __launch_bounds__(256) void k_scan_final(const int* __restrict__ deg2, const int* __restrict__ boff,
                                                    int* __restrict__ row_off, int* __restrict__ starts2,
                                                    int n) {
    __shared__ int s[256];
    int t = threadIdx.x;
    int i = blockIdx.x * 256 + t;
    uint4 d0 = make_uint4(0, 0, 0, 0), d1 = make_uint4(0, 0, 0, 0);
    int tot = 0;
    if (i < n) {
        d0 = *reinterpret_cast<const uint4*>(deg2 + (size_t)i * NCHUNK);
        d1 = *reinterpret_cast<const uint4*>(deg2 + (size_t)i * NCHUNK + 4);
        tot = (int)(d0.x + d0.y + d0.z + d0.w + d1.x + d1.y + d1.z + d1.w);
    }
    s[t] = tot;
    __syncthreads();
    for (int off = 1; off < 256; off <<= 1) {
        int x = (t >= off) ? s[t - off] : 0;
        __syncthreads();
        s[t] += x;
        __syncthreads();
    }
    int incl = s[t] + boff[blockIdx.x];
    if (i < n) {
        int r = incl - tot;
        row_off[i] = r;
        uint4 o0, o1;
        o0.x = r; r += d0.x;
        o0.y = r; r += d0.y;
        o0.z = r; r += d0.z;
        o0.w = r; r += d0.w;
        o1.x = r; r += d1.x;
        o1.y = r; r += d1.y;
        o1.z = r; r += d1.z;
        o1.w = r;
        *reinterpret_cast<uint4*>(starts2 + (size_t)i * NCHUNK) = o0;
        *reinterpret_cast<uint4*>(starts2 + (size_t)i * NCHUNK + 4) = o1;
        if (i == n - 1) row_off[n] = incl;
    }
}

// ---------------- launch E: CSR fill (chunk-ordered within each row) ----------------
__global__ __launch_bounds__(256) void k_fill(const int* __restrict__ src, const int* __restrict__ dst,
                                              const int* __restrict__ rank, const int* __restrict__ starts2,
                                              int* __restrict__ csrc, int E) {
    int e = blockIdx.x * 256 + threadIdx.x;
    if (e < E) {
        int s = src[e];
        int c = s >> CHUNK_SHIFT;
        csrc[starts2[dst[e] * NCHUNK + c] + rank[e]] = s;
    }
}

// ---------------- MFMA GEMM (layers 2/3): O = (X @ W) * dinv[row], bf16 ----------------
template <int NC>
__global__ __launch_bounds__(256) void k_gemm_mfma(const unsigned short* __restrict__ X,
                                                   const unsigned short* __restrict__ Wt,
                                                   const float* __restrict__ dinv,
                                                   unsigned short* __restrict__ O, int nrows) {
    constexpr int LDR = 136;
    __shared__ unsigned short sX[64 * LDR];
    __shared__ unsigned short sB[NC * LDR];

    const int tid  = threadIdx.x;
    const int row0 = blockIdx.x * 64;

#pragma unroll
    for (int i = 0; i < 4; ++i) {
        int idx = tid + i * 256;
        int r = idx >> 4, c8 = idx & 15;
        int grow = row0 + r;
        uint4 v = make_uint4(0, 0, 0, 0);
        if (grow < nrows) v = *reinterpret_cast<const uint4*>(X + (size_t)grow * 128 + c8 * 8);
        *reinterpret_cast<uint4*>(&sX[r * LDR + c8 * 8]) = v;
    }
#pragma unroll
    for (int i = 0; i < NC / 16; ++i) {
        int idx = tid + i * 256;
        int n = idx >> 4, c8 = idx & 15;
        *reinterpret_cast<uint4*>(&sB[n * LDR + c8 * 8]) =
            *reinterpret_cast<const uint4*>(Wt + (size_t)n * 128 + c8 * 8);
    }
    __syncthreads();

    const int lane = tid & 63;
    const int wave = tid >> 6;
    const int l15  = lane & 15;
    const int quad = lane >> 4;

    floatx4 acc[NC / 16];
#pragma unroll
    for (int j = 0; j < NC / 16; ++j) acc[j] = (floatx4){0.f, 0.f, 0.f, 0.f};

    const unsigned short* xbase = &sX[(wave * 16 + l15) * LDR + quad * 8];
#pragma unroll
    for (int kk = 0; kk < 4; ++kk) {
        short8 xb = *reinterpret_cast<const short8*>(xbase + kk * 32);
#pragma unroll
        for (int j = 0; j < NC / 16; ++j) {
            short8 wa = *reinterpret_cast<const short8*>(&sB[(j * 16 + l15) * LDR + quad * 8 + kk * 32]);
            acc[j] = __builtin_amdgcn_mfma_f32_16x16x32_bf16(wa, xb, acc[j], 0, 0, 0);
        }
    }

    int xrow = row0 + wave * 16 + l15;
    if (xrow < nrows) {
        float di = dinv[xrow];
#pragma unroll
        for (int j = 0; j < NC / 16; ++j) {
            uint2 o = make_uint2(f2bf2(acc[j][0] * di, acc[j][1] * di), f2bf2(acc[j][2] * di, acc[j][3] * di));
            *reinterpret_cast<uint2*>(O + (size_t)xrow * NC + j * 16 + quad * 4) = o;
        }
    }
}

// ---------------- aggregation (128 feats, pre-scaled bf16 H') + bias + relu ----------------
// 32 lanes/node: two 16-lane groups each aggregate HALF the neighbor list (doubles MLP,
// halves serial depth for the latency-bound gather), combined with one shfl_xor(16).
__global__ __launch_bounds__(256) void k_agg_relu(const unsigned short* __restrict__ H, const int* __restrict__ roff,
                                                  const int* __restrict__ csrc, const float* __restrict__ dinv,
                                                  const float* __restrict__ bias, unsigned short* __restrict__ O, int n) {
    int t      = blockIdx.x * 256 + threadIdx.x;
    int node   = t >> 5;
    int lane32 = t & 31;
    int half   = lane32 >> 4;
    int f8     = (lane32 & 15) * 8;
    if (node >= n) return;

    float a[8];
    if (half == 0) {
        uint4 hv = *reinterpret_cast<const uint4*>(H + (size_t)node * 128 + f8);
        unpack8(hv, a);  // self term H'[node]
    } else {
#pragma unroll
        for (int i = 0; i < 8; ++i) a[i] = 0.0f;
    }

    int e0 = roff[node];
    int e1 = roff[node + 1];
    int mid = e0 + ((e1 - e0) >> 1);
    int e  = half ? mid : e0;
    int ee = half ? e1 : mid;

    for (; e + 3 < ee; e += 4) {
        int s[4];
        uint4 v[4];
#pragma unroll
        for (int u = 0; u < 4; ++u) s[u] = csrc[e + u];
#pragma unroll
        for (int u = 0; u < 4; ++u) v[u] = *reinterpret_cast<const uint4*>(H + (size_t)s[u] * 128 + f8);
#pragma unroll
        for (int u = 0; u < 4; ++u) {
            float g2[8];
            unpack8(v[u], g2);
#pragma unroll
            for (int i = 0; i < 8; ++i) a[i] += g2[i];
        }
    }
    for (; e < ee; ++e) {
        uint4 v0 = *reinterpret_cast<const uint4*>(H + (size_t)csrc[e] * 128 + f8);
        float g0[8];
        unpack8(v0, g0);
#pragma unroll
        for (int i = 0; i < 8; ++i) a[i] += g0[i];
    }

    // combine the two half-list partial sums (lane ^ 16 stays within this node's 32 lanes)
#pragma unroll
    for (int i = 0; i < 8; ++i) a[i] += __shfl_xor(a[i], 16);

    if (half == 0) {
        float di = dinv[node];
        float4 b0 = ld4(bias + f8);
        float4 b1 = ld4(bias + f8 + 4);
        float bb[8] = {b0.x, b0.y, b0.z, b0.w, b1.x, b1.y, b1.z, b1.w};
#pragma unroll
        for (int i = 0; i < 8; ++i) a[i] = fmaxf(a[i] * di + bb[i], 0.0f);

        uint4 ov = make_uint4(f2bf2(a[0], a[1]), f2bf2(a[2], a[3]), f2bf2(a[4], a[5]), f2bf2(a[6], a[7]));
        *reinterpret_cast<uint4*>(O + (size_t)node * 128 + f8) = ov;
    }
}

// ---------------- aggregation (64 feats, pre-scaled bf16 H') + bias + log_softmax ----------------
// 16 lanes/node: two 8-lane groups each aggregate half the neighbor list; combine via shfl_xor(8).
__global__ __launch_bounds__(256) void k_agg_softmax(const unsigned short* __restrict__ H, const int* __restrict__ roff,
                                                     const int* __restrict__ csrc, const float* __restrict__ dinv,
                                                     const float* __restrict__ bias, float* __restrict__ O, int n) {
    int t      = blockIdx.x * 256 + threadIdx.x;
    int node   = t >> 4;
    int lane16 = t & 15;
    int half   = lane16 >> 3;
    int f8     = (lane16 & 7) * 8;
    if (node >= n) return;

    float a[8];
    if (half == 0) {
        uint4 hv = *reinterpret_cast<const uint4*>(H + (size_t)node * 64 + f8);
        unpack8(hv, a);  // self term
    } else {
#pragma unroll
        for (int i = 0; i < 8; ++i) a[i] = 0.0f;
    }

    int e0 = roff[node];
    int e1 = roff[node + 1];
    int mid = e0 + ((e1 - e0) >> 1);
    int e  = half ? mid : e0;
    int ee = half ? e1 : mid;

    for (; e + 3 < ee; e += 4) {
        int s[4];
        uint4 v[4];
#pragma unroll
        for (int u = 0; u < 4; ++u) s[u] = csrc[e + u];
#pragma unroll
        for (int u = 0; u < 4; ++u) v[u] = *reinterpret_cast<const uint4*>(H + (size_t)s[u] * 64 + f8);
#pragma unroll
        for (int u = 0; u < 4; ++u) {
            float gg[8];
            unpack8(v[u], gg);
#pragma unroll
            for (int i = 0; i < 8; ++i) a[i] += gg[i];
        }
    }
    for (; e < ee; ++e) {
        uint4 v0 = *reinterpret_cast<const uint4*>(H + (size_t)csrc[e] * 64 + f8);
        float g0[8];
        unpack8(v0, g0);
#pragma unroll
        for (int i = 0; i < 8; ++i) a[i] += g0[i];
    }

    // combine halves (lane ^ 8 stays within this node's 16 lanes)
#pragma unroll
    for (int i = 0; i < 8; ++i) a[i] += __shfl_xor(a[i], 8);

    if (half == 0) {
        float di = dinv[node];
        float4 b0 = ld4(bias + f8);
        float4 b1 = ld4(bias + f8 + 4);
        float bb[8] = {b0.x, b0.y, b0.z, b0.w, b1.x, b1.y, b1.z, b1.w};
        float v[8];
#pragma unroll
        for (int i = 0; i < 8; ++i) v[i] = a[i] * di + bb[i];

        float m = v[0];
#pragma unroll
        for (int i = 1; i < 8; ++i) m = fmaxf(m, v[i]);
        m = fmaxf(m, __shfl_xor(m, 1));
        m = fmaxf(m, __shfl_xor(m, 2));
        m = fmaxf(m, __shfl_xor(m, 4));

        float ssum = 0.0f;
#pragma unroll
        for (int i = 0; i < 8; ++i) ssum += expf(v[i] - m);
        ssum += __shfl_xor(ssum, 1);
        ssum += __shfl_xor(ssum, 2);
        ssum += __shfl_xor(ssum, 4);
        float ls = logf(ssum);

        float* op = O + (size_t)node * 64 + f8;
        st4(op, make_float4(v[0] - m - ls, v[1] - m - ls, v[2] - m - ls, v[3] - m - ls));
        st4(op + 4, make_float4(v[4] - m - ls, v[5] - m - ls, v[6] - m - ls, v[7] - m - ls));
    }
}

// ---------------- launch ----------------
extern "C" void kernel_launch(void* const* d_in, const int* in_sizes, int n_in,
                              void* d_out, int out_size, void* d_ws, size_t ws_size,
                              hipStream_t stream) {
    const float* x  = (const float*)d_in[0];
    const int*   ei = (const int*)d_in[1];
    const float* W1 = (const float*)d_in[2];
    const float* b1 = (const float*)d_in[3];
    const float* W2 = (const float*)d_in[4];
    const float* b2 = (const float*)d_in[5];
    const float* W3 = (const float*)d_in[6];
    const float* b3 = (const float*)d_in[7];
    float* out = (float*)d_out;

    const int N = in_sizes[0] / 128;
    const int E = in_sizes[1] / 2;
    const int* src = ei;
    const int* dst = ei + E;

    char* ws = (char*)d_ws;
    size_t off = 0;
    auto alloc = [&](size_t bytes) -> char* {
        char* p = ws + off;
        off = (off + bytes + 255) & ~(size_t)255;
        return p;
    };
    int nb  = (N + 255) / 256;
    int nbE = (E + 255) / 256;
    int blocks64 = (N + 63) / 64;

    int*   deg2    = (int*)alloc((size_t)N * NCHUNK * 4);
    int*   row_off = (int*)alloc(((size_t)N + 1) * 4);
    int*   starts2 = (int*)alloc((size_t)N * NCHUNK * 4);
    float* dinv    = (float*)alloc((size_t)N * 4);
    int*   bsum    = (int*)alloc((size_t)nb * 4);
    int*   boff    = (int*)alloc((size_t)nb * 4);
    int*   rank    = (int*)alloc((size_t)E * 4);
    int*   csrc    = (int*)alloc((size_t)E * 4);
    unsigned short* Wt1  = (unsigned short*)alloc(128 * 128 * 2);
    unsigned short* Wt2  = (unsigned short*)alloc(128 * 128 * 2);
    unsigned short* Wt3  = (unsigned short*)alloc(64 * 128 * 2);
    unsigned short* bufA = (unsigned short*)alloc((size_t)N * 128 * 2);
    unsigned short* bufB = (unsigned short*)alloc((size_t)N * 128 * 2);
    unsigned short* bufC = (unsigned short*)alloc((size_t)N * 64 * 2);
    (void)ws_size; (void)n_in; (void)out_size;

    hipMemsetAsync(deg2, 0, (size_t)N * NCHUNK * 4, stream);
    // A: edge count/rank per (dst,chunk) + W transposes
    k_count_prep<<<nbE + 160, 256, 0, stream>>>(src, dst, deg2, rank, E, nbE, W1, W2, W3, Wt1, Wt2, Wt3);
    // B: dinv + deg block-reduce
    k_dinv_reduce<<<nb + nb, 256, 0, stream>>>(deg2, dinv, bsum, N, nb);
    // C: scan_small (block 0) + layer-1 GEMM pre-scaled by dinv
    k_scansmall_gemm1<<<1 + blocks64, 256, 0, stream>>>(bsum, boff, nb, x, Wt1, dinv, bufA, N);
    // D: final scan -> row_off + starts2
    k_scan_final<<<nb, 256, 0, stream>>>(deg2, boff, row_off, starts2, N);
    // E: CSR fill (chunk-ordered)
    k_fill<<<nbE, 256, 0, stream>>>(src, dst, rank, starts2, csrc, E);

    // layer 1 aggregation (pre-scaled bufA), split-list 32 lanes/node
    k_agg_relu<<<((size_t)N * 32 + 255) / 256, 256, 0, stream>>>(bufA, row_off, csrc, dinv, b1, bufB, N);
    // layer 2 (epilogue scales by dinv)
    k_gemm_mfma<128><<<blocks64, 256, 0, stream>>>(bufB, Wt2, dinv, bufA, N);
    k_agg_relu<<<((size_t)N * 32 + 255) / 256, 256, 0, stream>>>(bufA, row_off, csrc, dinv, b2, bufB, N);
    // layer 3 + log_softmax
    k_gemm_mfma<64><<<blocks64, 256, 0, stream>>>(bufB, Wt3, dinv, bufC, N);
    k_agg_softmax<<<((size_t)N * 16 + 255) / 256, 256, 0, stream>>>(bufC, row_off, csrc, dinv, b3, out, N);
}